// Round 3
// baseline (221.152 us; speedup 1.0000x reference)
//
#include <hip/hip_runtime.h>
#include <math.h>

// Problem constants (from reference setup_inputs)
#define Bsz 16
#define Tsz 4
#define Nsz 1601
#define Dsz 1280
#define D4  (Dsz / 4)      // 320 float4 per row
#define ROWS_PER_BLK 50    // 33 chunks cover 1601 rows

// native clang vector type — accepted by __builtin_nontemporal_load/store
typedef float f32x4 __attribute__((ext_vector_type(4)));

// aspect_ratio is int64 in the reference; values are in {1,2}, so in an
// int64 LE buffer every odd int32 word is 0. Detect layout at runtime.
__device__ __forceinline__ void load_hw(const int* __restrict__ ar, int b, int& h, int& w) {
    int v0 = ar[2 * b];
    int v1 = ar[2 * b + 1];
    if (v1 != 0) {          // int32 layout: [h, w] directly
        h = v0; w = v1;
    } else {                // int64 layout: low words at 4b and 4b+2
        h = ar[4 * b];
        w = ar[4 * b + 2];
    }
}

// Kernel 1: materialize pe_scaled[bt][d] = valid ? emb[row,col,0,d]*tanh(gate) : 0
__global__ void build_pe_kernel(const f32x4* __restrict__ emb,
                                const int* __restrict__ ar,
                                const float* __restrict__ gate,
                                f32x4* __restrict__ pe) {
    int bt = blockIdx.x;            // 0..63
    int b = bt >> 2;
    int t = bt & 3;
    int h, w;
    load_hw(ar, b, h, w);
    float tg = tanhf(gate[0]);
    bool valid = t < h * w;
    int d4 = threadIdx.x;           // 0..319
    f32x4 v = (f32x4)(0.f);
    if (valid) {
        int row = t / w;
        int col = t % w;
        v = emb[(row * Tsz + col) * D4 + d4] * tg;
    }
    pe[bt * D4 + d4] = v;
}

// Kernel 2: streaming add, row-chunked.
// grid = (ceil(N/ROWS_PER_BLK), B*T) = (33,64), block = 320 threads (5 waves).
// Each block: pe row in registers (one load), stream ROWS_PER_BLK rows with
// nontemporal 16B load/store (single-use data, skip cache), unroll x2.
__global__ void add_pe_kernel(const f32x4* __restrict__ x,
                              const f32x4* __restrict__ pe,
                              f32x4* __restrict__ out) {
    int bt = blockIdx.y;
    int r0 = blockIdx.x * ROWS_PER_BLK;
    int nrows = min(ROWS_PER_BLK, Nsz - r0);
    f32x4 pv = pe[bt * D4 + threadIdx.x];
    long base = ((long)bt * Nsz + r0) * D4 + threadIdx.x;

    int g = 0;
    for (; g + 1 < nrows; g += 2) {
        f32x4 a = __builtin_nontemporal_load(&x[base + (long)g * D4]);
        f32x4 c = __builtin_nontemporal_load(&x[base + (long)(g + 1) * D4]);
        a += pv;
        c += pv;
        __builtin_nontemporal_store(a, &out[base + (long)g * D4]);
        __builtin_nontemporal_store(c, &out[base + (long)(g + 1) * D4]);
    }
    if (g < nrows) {
        f32x4 a = __builtin_nontemporal_load(&x[base + (long)g * D4]);
        a += pv;
        __builtin_nontemporal_store(a, &out[base + (long)g * D4]);
    }
}

extern "C" void kernel_launch(void* const* d_in, const int* in_sizes, int n_in,
                              void* d_out, int out_size, void* d_ws, size_t ws_size,
                              hipStream_t stream) {
    const f32x4* x    = (const f32x4*)d_in[0];   // (B,T,N,D) fp32
    const int*   ar   = (const int*)d_in[1];     // (B,2) int
    const f32x4* emb  = (const f32x4*)d_in[2];   // (T,T,1,D) fp32
    const float* gate = (const float*)d_in[3];   // (1,) fp32
    f32x4* out = (f32x4*)d_out;

    f32x4* pe = (f32x4*)d_ws;                    // 327,680 B << ws_size
    build_pe_kernel<<<dim3(Bsz * Tsz), D4, 0, stream>>>(emb, ar, gate, pe);
    int chunks = (Nsz + ROWS_PER_BLK - 1) / ROWS_PER_BLK;   // 33
    add_pe_kernel<<<dim3(chunks, Bsz * Tsz), D4, 0, stream>>>(x, pe, out);
}

// Round 4
// 209.891 us; speedup vs baseline: 1.0537x; 1.0537x over previous
//
#include <hip/hip_runtime.h>
#include <math.h>

// Problem constants (from reference setup_inputs)
#define Bsz 16
#define Tsz 4
#define Nsz 1601
#define Dsz 1280
#define D4  (Dsz / 4)      // 320 float4 per row
#define GRIDX 24           // 24 x 64 = 1536 blocks = exactly the resident set
                           // (320 thr = 5 waves; 6 blocks/CU x 256 CU = 1536)

// native clang vector type — accepted by __builtin_nontemporal_load/store
typedef float f32x4 __attribute__((ext_vector_type(4)));

// aspect_ratio is int64 in the reference; values are in {1,2}, so in an
// int64 LE buffer every odd int32 word is 0. Detect layout at runtime.
__device__ __forceinline__ void load_hw(const int* __restrict__ ar, int b, int& h, int& w) {
    int v0 = ar[2 * b];
    int v1 = ar[2 * b + 1];
    if (v1 != 0) {          // int32 layout: [h, w] directly
        h = v0; w = v1;
    } else {                // int64 layout: low words at 4b and 4b+2
        h = ar[4 * b];
        w = ar[4 * b + 2];
    }
}

// Fused persistent kernel. grid = (GRIDX, B*T), block = 320 threads.
// Each block: compute its slab's pe row once (tanh + one 16B emb load/thread,
// L2-hot), then grid-stride over rows blockIdx.x, +GRIDX, ... with
// nontemporal 16B streams, 2-deep software pipeline.
__global__ void add_pe_kernel(const f32x4* __restrict__ x,
                              const f32x4* __restrict__ emb,
                              const int* __restrict__ ar,
                              const float* __restrict__ gate,
                              f32x4* __restrict__ out) {
    int bt = blockIdx.y;            // 0..63
    int b = bt >> 2;
    int t = bt & 3;
    int h, w;
    load_hw(ar, b, h, w);
    float tg = tanhf(gate[0]);
    f32x4 pv = (f32x4)(0.f);
    if (t < h * w) {
        int row = t / w;
        int col = t % w;
        pv = emb[(row * Tsz + col) * D4 + threadIdx.x] * tg;
    }

    const long stride = (long)GRIDX * D4;
    long off = (long)bt * Nsz * D4 + (long)blockIdx.x * D4 + threadIdx.x;
    const long end = ((long)bt + 1) * Nsz * D4;

    // rows r = blockIdx.x + k*GRIDX while r < Nsz; two rows per iteration
    for (; off + stride < end; off += 2 * stride) {
        f32x4 a = __builtin_nontemporal_load(&x[off]);
        f32x4 c = __builtin_nontemporal_load(&x[off + stride]);
        a += pv;
        c += pv;
        __builtin_nontemporal_store(a, &out[off]);
        __builtin_nontemporal_store(c, &out[off + stride]);
    }
    if (off < end) {
        f32x4 a = __builtin_nontemporal_load(&x[off]);
        a += pv;
        __builtin_nontemporal_store(a, &out[off]);
    }
}

extern "C" void kernel_launch(void* const* d_in, const int* in_sizes, int n_in,
                              void* d_out, int out_size, void* d_ws, size_t ws_size,
                              hipStream_t stream) {
    const f32x4* x    = (const f32x4*)d_in[0];   // (B,T,N,D) fp32
    const int*   ar   = (const int*)d_in[1];     // (B,2) int
    const f32x4* emb  = (const f32x4*)d_in[2];   // (T,T,1,D) fp32
    const float* gate = (const float*)d_in[3];   // (1,) fp32
    f32x4* out = (f32x4*)d_out;

    add_pe_kernel<<<dim3(GRIDX, Bsz * Tsz), D4, 0, stream>>>(x, emb, ar, gate, out);
}